// Round 6
// baseline (79.942 us; speedup 1.0000x reference)
//
#include <hip/hip_runtime.h>
#include <math.h>

#define A_CUBIC (-0.75f)
#define NB 2
#define NC 3
#define HH 144
#define NPB 2304      // patches per batch (48*48)
#define GG 14460      // database patches per batch
#define DD 27
#define DP 28         // padded row stride; row[27] holds gn (for gf) or -1 (for m)
#define GSPLIT 128
#define GTILE 113     // ceil(14460/128)

typedef float v2f __attribute__((ext_vector_type(2)));

__constant__ int c_seg_start[15] = {0,2209,2738,2859,5068,5597,5718,7927,8456,8577,10786,11315,11436,13740,14316};
__constant__ int c_seg_gw[15]    = {47,23,11, 47,23,11, 47,23,11, 47,23,11, 48,24,12};
__constant__ int c_seg_oy[15]    = {1,1,1, 1,1,1, 2,2,2, 2,2,2, 0,0,0};
__constant__ int c_seg_ox[15]    = {1,1,1, 2,2,2, 1,1,1, 2,2,2, 0,0,0};
__constant__ int c_seg_src[15]   = {0,1,2, 0,1,2, 0,1,2, 0,1,2, 0,1,2};

__device__ __forceinline__ float cubicw(float t) {
    float at = fabsf(t);
    if (at <= 1.0f) return ((A_CUBIC + 2.0f) * at - (A_CUBIC + 3.0f)) * at * at + 1.0f;
    if (at < 2.0f)  return A_CUBIC * (((at - 5.0f) * at + 8.0f) * at - 4.0f);
    return 0.0f;
}

// K1: bicubic downscale tar -> s1 (72x72), s2 (36x36), PLUS m-row build + best init.
__global__ void prep_k(const float* __restrict__ tar, const float* __restrict__ inp,
                       float* __restrict__ s1, float* __restrict__ s2,
                       float* __restrict__ m, unsigned long long* __restrict__ best) {
    int t = blockIdx.x * 256 + threadIdx.x;
    const int total1 = NB * NC * 72 * 72;
    const int total2 = NB * NC * 36 * 36;
    if (t < total1 + total2) {
        float* dst; int O; int idx;
        if (t < total1) { dst = s1; O = 72; idx = t; }
        else            { dst = s2; O = 36; idx = t - total1; }
        int x  = idx % O;
        int y  = (idx / O) % O;
        int bc = idx / (O * O);
        const float* src = tar + (size_t)bc * HH * HH;
        float scale = (float)(143.0 / (double)(O - 1));
        float fy = (float)y * scale;
        float iyf = floorf(fy); float fry = fy - iyf; int iy = (int)iyf;
        float fx = (float)x * scale;
        float ixf = floorf(fx); float frx = fx - ixf; int ix = (int)ixf;
        float wy[4], wx[4];
        #pragma unroll
        for (int d = 0; d < 4; ++d) {
            wy[d] = cubicw(fry - (float)(d - 1));
            wx[d] = cubicw(frx - (float)(d - 1));
        }
        float acc = 0.0f;
        #pragma unroll
        for (int dx = 0; dx < 4; ++dx) {
            int cx = min(max(ix - 1 + dx, 0), HH - 1);
            float inner = 0.0f;
            #pragma unroll
            for (int dy = 0; dy < 4; ++dy) {
                int cy = min(max(iy - 1 + dy, 0), HH - 1);
                inner += wy[dy] * src[cy * HH + cx];
            }
            acc += wx[dx] * inner;
        }
        dst[idx] = acc;
    } else {
        int u = t - (total1 + total2);
        if (u >= NB * NPB) return;
        int b = u / NPB, n = u % NPB;
        int hc = n / 48, wc = n % 48;
        const float* ib = inp + (size_t)b * NC * HH * HH;
        const float* tb = tar + (size_t)b * NC * HH * HH;
        float* row = m + (size_t)u * DP;
        #pragma unroll
        for (int c = 0; c < 3; ++c)
            #pragma unroll
            for (int dy = 0; dy < 3; ++dy)
                #pragma unroll
                for (int dx = 0; dx < 3; ++dx) {
                    int off = (c * HH + hc * 3 + dy) * HH + wc * 3 + dx;
                    row[(c * 3 + dy) * 3 + dx] = ib[off] + tb[off];
                }
        row[27] = -1.0f;
        best[u] = 0ULL;
    }
}

// K2: build gf database rows [B*G][28]; row[27] = |g|^2
__global__ void build_gf_k(const float* __restrict__ tar, const float* __restrict__ s1,
                           const float* __restrict__ s2, float* __restrict__ gf) {
    int t = blockIdx.x * 256 + threadIdx.x;
    if (t >= NB * GG) return;
    int b = t / GG, g = t % GG;
    int s = 0;
    #pragma unroll
    for (int k = 1; k < 15; ++k) if (g >= c_seg_start[k]) s = k;
    int p  = g - c_seg_start[s];
    int gw = c_seg_gw[s];
    int hc = p / gw, wc = p % gw;
    int oy = c_seg_oy[s], ox = c_seg_ox[s];
    int srci = c_seg_src[s];
    const float* img; int sz;
    if (srci == 0)      { img = tar; sz = 144; }
    else if (srci == 1) { img = s1;  sz = 72;  }
    else                { img = s2;  sz = 36;  }
    const float* base = img + (size_t)b * NC * sz * sz;
    int y0 = oy + hc * 3, x0 = ox + wc * 3;
    float acc = 0.0f;
    float* row = gf + (size_t)t * DP;
    #pragma unroll
    for (int c = 0; c < 3; ++c)
        #pragma unroll
        for (int dy = 0; dy < 3; ++dy)
            #pragma unroll
            for (int dx = 0; dx < 3; ++dx) {
                float v = base[((size_t)c * sz + y0 + dy) * sz + x0 + dx];
                row[(c * 3 + dy) * 3 + dx] = v;
                acc = fmaf(v, v, acc);
            }
    row[27] = acc;
}

__device__ __forceinline__ float dot28(const v2f mr[14], const v2f r[14]) {
    v2f a0 = {0.0f, 0.0f}, a1 = {0.0f, 0.0f};
    #pragma unroll
    for (int i = 0; i < 14; i += 2) {
        a0 = __builtin_elementwise_fma(mr[i],     r[i],     a0);
        a1 = __builtin_elementwise_fma(mr[i + 1], r[i + 1], a1);
    }
    v2f t = a0 + a1;
    return t.x + t.y;
}

// K4: one n per thread (28 VGPR m-row), g-rows via wave-uniform s_load
// ping-pong. 2304 blocks -> 32 waves/CU: s_load latency hidden by TLP.
__global__ __launch_bounds__(256, 8) void argmin_k(
        const float* __restrict__ gf, const float* __restrict__ m,
        unsigned long long* __restrict__ best) {
    int tid = threadIdx.x;
    int nblk = blockIdx.y;              // 0..17 (256 n each)
    int b  = nblk / 9;
    int nn = nblk * 256 + tid;          // global n index (b*NPB + n)
    const v2f* mrow = (const v2f*)(m + (size_t)nn * DP);
    v2f mr[14];
    #pragma unroll
    for (int i = 0; i < 14; ++i) mr[i] = mrow[i];
    int g0 = blockIdx.x * GTILE;
    int g1 = min(g0 + GTILE, GG);
    const float* gfb = gf + (size_t)b * GG * DP;
    float bv = -3.0e38f; int bi = 0;

    v2f A[14], B[14];
    {
        const v2f* p = (const v2f*)(gfb + (size_t)g0 * DP);
        #pragma unroll
        for (int i = 0; i < 14; ++i) A[i] = p[i];
    }
    int g = g0;
    for (; g + 1 < g1; g += 2) {
        {   // prefetch row g+1
            const v2f* p = (const v2f*)(gfb + (size_t)(g + 1) * DP);
            #pragma unroll
            for (int i = 0; i < 14; ++i) B[i] = p[i];
        }
        float s = dot28(mr, A);
        if (s > bv) { bv = s; bi = g; }       // strict >: keeps first max
        {   // prefetch row g+2 (overreads <=1 row past gf into m; harmless)
            const v2f* p = (const v2f*)(gfb + (size_t)(g + 2) * DP);
            #pragma unroll
            for (int i = 0; i < 14; ++i) A[i] = p[i];
        }
        float s2 = dot28(mr, B);
        if (s2 > bv) { bv = s2; bi = g + 1; }
    }
    if (g < g1) {
        float s = dot28(mr, A);
        if (s > bv) { bv = s; bi = g; }
    }
    // monotonic float encoding; low word ~g so equal scores prefer smaller g
    unsigned u = __float_as_uint(bv);
    u ^= (unsigned)(((int)u >> 31)) | 0x80000000u;
    atomicMax(&best[nn], ((unsigned long long)u << 32) | (unsigned)(~bi));
}

// K5: decode best, gather sel, fold to image, block-partial L1 sums
__global__ void finalize_k(const float* __restrict__ gf,
                           const unsigned long long* __restrict__ best,
                           const float* __restrict__ inp,
                           float* __restrict__ out, float* __restrict__ lpart) {
    __shared__ float red[256];
    int t = blockIdx.x * 256 + threadIdx.x;
    float lsum = 0.0f;
    if (t < NB * NPB) {
        int b = t / NPB, n = t % NPB;
        unsigned long long pk = best[t];
        int bi = (int)(~(unsigned)(pk & 0xFFFFFFFFull));
        int hc = n / 48, wc = n % 48;
        const float* grow = gf + ((size_t)b * GG + bi) * DP;
        const float* ib   = inp + (size_t)b * NC * HH * HH;
        float* sel = out + 1 + (size_t)b * NC * HH * HH;
        #pragma unroll
        for (int c = 0; c < 3; ++c)
            #pragma unroll
            for (int dy = 0; dy < 3; ++dy)
                #pragma unroll
                for (int dx = 0; dx < 3; ++dx) {
                    int d = (c * 3 + dy) * 3 + dx;
                    float sv = grow[d];
                    int off = (c * HH + hc * 3 + dy) * HH + wc * 3 + dx;
                    sel[off] = sv;
                    lsum += fabsf(ib[off] - sv);
                }
    }
    red[threadIdx.x] = lsum;
    __syncthreads();
    for (int s = 128; s > 0; s >>= 1) {
        if (threadIdx.x < s) red[threadIdx.x] += red[threadIdx.x + s];
        __syncthreads();
    }
    if (threadIdx.x == 0) lpart[blockIdx.x] = red[0];
}

// K6: scalar loss mean
__global__ void sum_k(const float* __restrict__ lpart, float* __restrict__ out) {
    if (threadIdx.x == 0) {
        float s = 0.0f;
        for (int i = 0; i < 18; ++i) s += lpart[i];
        out[0] = s * (1.0f / 124416.0f);
    }
}

extern "C" void kernel_launch(void* const* d_in, const int* in_sizes, int n_in,
                              void* d_out, int out_size, void* d_ws, size_t ws_size,
                              hipStream_t stream) {
    const float* inp = (const float*)d_in[0];
    const float* tar = (const float*)d_in[1];
    float* out = (float*)d_out;
    float* ws  = (float*)d_ws;

    float* s1 = ws;                       // 31104
    float* s2 = s1 + 31104;               // 7776
    float* gf = s2 + 7776;                // 2*14460*28 = 809760
    float* m  = gf + 809760;              // 2*2304*28 = 129024
    unsigned long long* best = (unsigned long long*)(m + 129024);  // 4608 u64
    float* lp = (float*)(best + 4608);    // 18

    prep_k    <<<(43488 + 255) / 256, 256, 0, stream>>>(tar, inp, s1, s2, m, best);
    build_gf_k<<<(28920 + 255) / 256, 256, 0, stream>>>(tar, s1, s2, gf);
    argmin_k  <<<dim3(GSPLIT, 18), 256, 0, stream>>>(gf, m, best);
    finalize_k<<<18, 256, 0, stream>>>(gf, best, inp, out, lp);
    sum_k     <<<1, 64, 0, stream>>>(lp, out);
}